// Round 1
// baseline (464.398 us; speedup 1.0000x reference)
//
#include <hip/hip_runtime.h>
#include <math.h>
#include <stdint.h>
#include <stddef.h>

// ---------- types ----------
typedef short bf16x8 __attribute__((ext_vector_type(8)));   // 8 bf16 (4 VGPRs)
typedef short bf16x4 __attribute__((ext_vector_type(4)));   // 4 bf16 (2 VGPRs)
typedef float f32x4  __attribute__((ext_vector_type(4)));

// problem constants
#define BATCH   8
#define M_IN    8192
#define D_IN    1024
#define POSD    32
#define KD      1056          // D_IN + POSD (inner GEMM dim)
#define MBARS   2048          // M_IN / 4
#define MROWS   16384         // BATCH * MBARS
#define NOUT    1024

// fp32 -> bf16 round-to-nearest-even (inputs are finite randoms; no NaN path)
__device__ __forceinline__ short f2bf(float f) {
    unsigned u = __builtin_bit_cast(unsigned, f);
    u += 0x7fffu + ((u >> 16) & 1u);
    return (short)(u >> 16);
}

// async global -> LDS, 16B per lane; LDS dest = wave-uniform base + lane*16
__device__ __forceinline__ void async_load16(const short* g, short* l) {
    __builtin_amdgcn_global_load_lds((__attribute__((address_space(1))) void*)g,
                                     (__attribute__((address_space(3))) void*)l,
                                     16, 0, 0);
}

// ---------- kernel 1: cast W [1024,1056] fp32 -> bf16 ----------
__global__ __launch_bounds__(256) void wcast(const float* __restrict__ W,
                                             short* __restrict__ Wb) {
    int i = blockIdx.x * 256 + threadIdx.x;        // 1056*256 = 270336 float4s exactly
    float4 v = ((const float4*)W)[i];
    bf16x4 o = { f2bf(v.x), f2bf(v.y), f2bf(v.z), f2bf(v.w) };
    ((bf16x4*)Wb)[i] = o;
}

// ---------- kernel 2: segment mean (K=4) + fourier features -> h bf16 [16384,1056] ----------
__global__ __launch_bounds__(256) void pool_ff(const float* __restrict__ x,
                                               short* __restrict__ h) {
    const int row = blockIdx.x;                    // 0..16383  (= b*2048 + mb)
    const int t   = threadIdx.x;                   // 0..255
    // rows mb*4 .. mb*4+3 of batch b are 16KB contiguous starting at row*4096 floats
    const float4* src = (const float4*)(x + (size_t)row * 4096);
    float4 s0 = src[t];
    float4 s1 = src[t + 256];
    float4 s2 = src[t + 512];
    float4 s3 = src[t + 768];
    float mx = (s0.x + s1.x + s2.x + s3.x) * 0.25f;
    float my = (s0.y + s1.y + s2.y + s3.y) * 0.25f;
    float mz = (s0.z + s1.z + s2.z + s3.z) * 0.25f;
    float mw = (s0.w + s1.w + s2.w + s3.w) * 0.25f;
    bf16x4 o = { f2bf(mx), f2bf(my), f2bf(mz), f2bf(mw) };
    *(bf16x4*)(h + (size_t)row * KD + t * 4) = o;

    if (t < POSD) {
        const int mb = row & (MBARS - 1);
        float pos = (float)mb * (1.0f / (float)(MBARS - 1));   // in [0,1], no clip needed
        // freqs[i] = exp(i * log(1000)/15), i = t&15 for both sin and cos halves
        float fr  = expf((float)(t & 15) * (6.907755278982137f / 15.0f));
        float ang = pos * fr;
        float v   = (t < 16) ? sinf(ang) : cosf(ang);
        h[(size_t)row * KD + D_IN + t] = f2bf(v);
    }
}

// ---------- kernel 3: C[16384,1024] = h[16384,1056] @ Wb^T + bias ----------
// m97 structure: 128x128 tile, BK=32, 4 waves in 2x2, each wave 4x4 of 16x16x32 MFMA.
__global__ __launch_bounds__(256) void gemm_bt(const short* __restrict__ A,   // h  [MROWS, KD] bf16
                                               const short* __restrict__ B,   // Wb [NOUT, KD] bf16 (= B^T layout)
                                               const float* __restrict__ bias,
                                               float* __restrict__ C) {
    __shared__ short As[128 * 32];   // 8 KB, row-major [m][k], NO padding (global_load_lds layout)
    __shared__ short Bs[128 * 32];   // 8 KB, row-major [n][k]

    const int tid  = threadIdx.x;
    const int wave = tid >> 6;
    const int lane = tid & 63;
    const int wrow = wave >> 1;          // 2x2 wave grid -> 64x64 per wave
    const int wcol = wave & 1;

    const int m0 = blockIdx.x * 128;     // gridDim.x = 128
    const int n0 = blockIdx.y * 128;     // gridDim.y = 8

    // staging: per issue, 256 thr x 16B = 64 rows x 32 cols
    const int srow = tid >> 2;           // 0..63
    const int scol = (tid & 3) << 3;     // 0,8,16,24
    const short* ag = A + (size_t)(m0 + srow) * KD + scol;
    const short* bg = B + (size_t)(n0 + srow) * KD + scol;
    short* al = As + wave * (16 * 32);   // wave-uniform LDS base; lane writes +lane*8 elems
    short* bl = Bs + wave * (16 * 32);

    // fragment addresses: lane holds row (lane&15), k = (lane>>4)*8 .. +8 (ds_read_b128)
    const int foff = ((lane & 15) << 5) + ((lane >> 4) << 3);
    const short* afrag = As + wrow * (64 * 32) + foff;
    const short* bfrag = Bs + wcol * (64 * 32) + foff;

    f32x4 acc[4][4] = {};

    for (int k0 = 0; k0 < KD; k0 += 32) {          // 33 iterations
        __syncthreads();                            // LDS reuse-safe
        async_load16(ag + k0,            al);
        async_load16(ag + k0 + 64 * KD,  al + 64 * 32);
        async_load16(bg + k0,            bl);
        async_load16(bg + k0 + 64 * KD,  bl + 64 * 32);
        __syncthreads();                            // drains vmcnt -> tile visible

        bf16x8 a[4], b[4];
#pragma unroll
        for (int i = 0; i < 4; ++i) {
            a[i] = *(const bf16x8*)(afrag + i * (16 * 32));
            b[i] = *(const bf16x8*)(bfrag + i * (16 * 32));
        }
#pragma unroll
        for (int i = 0; i < 4; ++i)
#pragma unroll
            for (int j = 0; j < 4; ++j)
                acc[i][j] = __builtin_amdgcn_mfma_f32_16x16x32_bf16(a[i], b[j], acc[i][j], 0, 0, 0);
    }

    // epilogue: C/D layout col = lane&15, row = (lane>>4)*4 + reg  [m89/m91]
    const int r0 = m0 + wrow * 64 + ((lane >> 4) << 2);
    const int c0 = n0 + wcol * 64 + (lane & 15);
#pragma unroll
    for (int j = 0; j < 4; ++j) {
        const int col = c0 + j * 16;
        const float bv = bias[col];
#pragma unroll
        for (int i = 0; i < 4; ++i) {
            float* cp = C + (size_t)(r0 + i * 16) * NOUT + col;
#pragma unroll
            for (int r = 0; r < 4; ++r)
                cp[(size_t)r * NOUT] = acc[i][j][r] + bv;
        }
    }
}

extern "C" void kernel_launch(void* const* d_in, const int* in_sizes, int n_in,
                              void* d_out, int out_size, void* d_ws, size_t ws_size,
                              hipStream_t stream) {
    const float* x    = (const float*)d_in[0];   // [8, 8192, 1024]
    const float* W    = (const float*)d_in[1];   // [1024, 1056]
    const float* bias = (const float*)d_in[2];   // [1024]
    float* out = (float*)d_out;                  // [8, 2048, 1024]

    // workspace layout: Wb bf16 [1024*1056] then h bf16 [16384*1056]
    short* Wb = (short*)d_ws;
    short* h  = (short*)((char*)d_ws + (size_t)NOUT * KD * sizeof(short));  // offset 2,162,688 B (16B aligned)

    wcast  <<<dim3(KD), dim3(256), 0, stream>>>(W, Wb);
    pool_ff<<<dim3(MROWS), dim3(256), 0, stream>>>(x, h);
    gemm_bt<<<dim3(MROWS / 128, NOUT / 128), dim3(256), 0, stream>>>(h, Wb, bias, out);
}

// Round 2
// 423.119 us; speedup vs baseline: 1.0976x; 1.0976x over previous
//
#include <hip/hip_runtime.h>
#include <math.h>
#include <stdint.h>
#include <stddef.h>

// ---------- types ----------
typedef short bf16x8 __attribute__((ext_vector_type(8)));   // 8 bf16 (4 VGPRs)
typedef short bf16x4 __attribute__((ext_vector_type(4)));   // 4 bf16 (2 VGPRs)
typedef float f32x4  __attribute__((ext_vector_type(4)));

// problem constants
#define BATCH   8
#define D_IN    1024
#define POSD    32
#define KD      1056          // D_IN + POSD (true inner dim)
#define KP      1088          // K padded to multiple of 64 (pad cols are zero)
#define MBARS   2048
#define MROWS   16384         // BATCH * MBARS
#define NOUT    1024

// fp32 -> bf16 round-to-nearest-even
__device__ __forceinline__ short f2bf(float f) {
    unsigned u = __builtin_bit_cast(unsigned, f);
    u += 0x7fffu + ((u >> 16) & 1u);
    return (short)(u >> 16);
}

// async global -> LDS, 16B/lane; LDS dest = wave-uniform base + lane*16
__device__ __forceinline__ void async_load16(const short* g, short* l) {
    __builtin_amdgcn_global_load_lds((__attribute__((address_space(1))) void*)g,
                                     (__attribute__((address_space(3))) void*)l,
                                     16, 0, 0);
}

// ---------- kernel 1: fused prep ----------
// blocks [0, MROWS): segment-mean (K=4) + fourier features -> h row (stride KP, zero-padded)
// blocks [MROWS, MROWS+1024): W fp32 -> bf16 row cast (stride KP, zero-padded)
__global__ __launch_bounds__(256) void prep(const float* __restrict__ x,
                                            const float* __restrict__ W,
                                            short* __restrict__ h,
                                            short* __restrict__ Wb) {
    const int t = threadIdx.x;
    const int bid = blockIdx.x;
    if (bid < MROWS) {
        // 4 input rows are 16 KB contiguous at x + bid*4096
        const float4* src = (const float4*)(x + (size_t)bid * 4096);
        float4 s0 = src[t], s1 = src[t + 256], s2 = src[t + 512], s3 = src[t + 768];
        bf16x4 o = { f2bf((s0.x + s1.x + s2.x + s3.x) * 0.25f),
                     f2bf((s0.y + s1.y + s2.y + s3.y) * 0.25f),
                     f2bf((s0.z + s1.z + s2.z + s3.z) * 0.25f),
                     f2bf((s0.w + s1.w + s2.w + s3.w) * 0.25f) };
        short* hr = h + (size_t)bid * KP;
        *(bf16x4*)(hr + t * 4) = o;
        if (t < POSD) {
            const int mb = bid & (MBARS - 1);
            float pos = (float)mb * (1.0f / (float)(MBARS - 1));
            float fr  = expf((float)(t & 15) * (6.907755278982137f / 15.0f));
            float ang = pos * fr;
            hr[D_IN + t] = f2bf((t < 16) ? sinf(ang) : cosf(ang));
            hr[KD + t]   = 0;            // K padding
        }
    } else {
        const int r = bid - MROWS;       // 0..1023, one W row per block
        const float* wr = W + (size_t)r * KD;
        short* br = Wb + (size_t)r * KP;
        float4 v = *(const float4*)(wr + t * 4);          // cols 0..1023
        bf16x4 o = { f2bf(v.x), f2bf(v.y), f2bf(v.z), f2bf(v.w) };
        *(bf16x4*)(br + t * 4) = o;
        if (t < 8) {
            float4 u = *(const float4*)(wr + 1024 + t * 4);  // cols 1024..1055
            bf16x4 p = { f2bf(u.x), f2bf(u.y), f2bf(u.z), f2bf(u.w) };
            *(bf16x4*)(br + 1024 + t * 4) = p;
            *(bf16x4*)(br + KD + t * 4)   = (bf16x4){0, 0, 0, 0};  // K padding
        }
    }
}

// ---------- kernel 2: C[16384,1024] = h[16384,KP] @ Wb^T + bias ----------
// 128x128 tile, BK=64 (17 iters, half the barriers of BK=32), 2x2 waves x (4x4 of 16x16x32 MFMA).
// LDS layout XOR-swizzled via the GLOBAL source octet (global_load_lds can't scatter LDS side):
//   LDS slot j of row r holds global k-octet (j ^ (r&7)); fragment reads hit 2 lanes/bank = free.
__global__ __launch_bounds__(256) void gemm_bt(const short* __restrict__ A,   // h  [MROWS, KP]
                                               const short* __restrict__ B,   // Wb [NOUT, KP]
                                               const float* __restrict__ bias,
                                               float* __restrict__ C) {
    __shared__ short As[128 * 64];   // 16 KB, swizzled row-major [m][k]
    __shared__ short Bs[128 * 64];   // 16 KB

    const int tid  = threadIdx.x;
    const int wave = tid >> 6;
    const int lane = tid & 63;
    const int wrow = wave >> 1;          // 2x2 wave grid -> 64x64 per wave
    const int wcol = wave & 1;

    const int m0 = blockIdx.x * 128;     // gridDim.x = 128
    const int n0 = blockIdx.y * 128;     // gridDim.y = 8

    // staging: issue covers 32 rows x 64 cols; thread t -> row t>>3, octet (t&7)^swizzle
    const int r8   = tid >> 3;                    // 0..31
    const int soct = (tid & 7) ^ (r8 & 7);        // swizzled global octet
    const short* ag = A + (size_t)(m0 + r8) * KP + soct * 8;
    const short* bg = B + (size_t)(n0 + r8) * KP + soct * 8;
    short* al = As + wave * 512;                  // wave-uniform; HW adds lane*16B
    short* bl = Bs + wave * 512;

    // fragment decode
    const int r  = lane & 15;
    const int q  = lane >> 4;                     // k-octet within 32-wide step
    const int rx = r & 7;
    const short* afr = As + (wrow * 64 + r) * 64;
    const short* bfr = Bs + (wcol * 64 + r) * 64;
    const int sl0 = ((q    ) ^ rx) * 8;           // s=0: k-octets 0..3
    const int sl1 = ((4 + q) ^ rx) * 8;           // s=1: k-octets 4..7

    f32x4 acc[4][4] = {};

    for (int k0 = 0; k0 < KP; k0 += 64) {         // 17 iterations
        __syncthreads();
#pragma unroll
        for (int i = 0; i < 4; ++i) {             // 4 issues x 32 rows each, A and B
            async_load16(ag + k0 + (size_t)i * 32 * KP, al + i * 2048);
            async_load16(bg + k0 + (size_t)i * 32 * KP, bl + i * 2048);
        }
        __syncthreads();

#pragma unroll
        for (int s = 0; s < 2; ++s) {
            const int sl = s ? sl1 : sl0;
            bf16x8 a[4], b[4];
#pragma unroll
            for (int i = 0; i < 4; ++i) {
                a[i] = *(const bf16x8*)(afr + i * 1024 + sl);
                b[i] = *(const bf16x8*)(bfr + i * 1024 + sl);
            }
#pragma unroll
            for (int i = 0; i < 4; ++i)
#pragma unroll
                for (int j = 0; j < 4; ++j)
                    acc[i][j] = __builtin_amdgcn_mfma_f32_16x16x32_bf16(a[i], b[j], acc[i][j], 0, 0, 0);
        }
    }

    // epilogue: C/D layout col = lane&15, row = (lane>>4)*4 + reg
    const int rr0 = m0 + wrow * 64 + (q << 2);
    const int c0  = n0 + wcol * 64 + r;
    float bv[4];
#pragma unroll
    for (int j = 0; j < 4; ++j) bv[j] = bias[c0 + j * 16];
#pragma unroll
    for (int i = 0; i < 4; ++i)
#pragma unroll
        for (int rg = 0; rg < 4; ++rg) {
            float* cp = C + (size_t)(rr0 + i * 16 + rg) * NOUT;
#pragma unroll
            for (int j = 0; j < 4; ++j)
                cp[c0 + j * 16] = acc[i][j][rg] + bv[j];
        }
}

extern "C" void kernel_launch(void* const* d_in, const int* in_sizes, int n_in,
                              void* d_out, int out_size, void* d_ws, size_t ws_size,
                              hipStream_t stream) {
    const float* x    = (const float*)d_in[0];   // [8, 8192, 1024]
    const float* W    = (const float*)d_in[1];   // [1024, 1056]
    const float* bias = (const float*)d_in[2];   // [1024]
    float* out = (float*)d_out;                  // [8, 2048, 1024]

    // workspace: Wb bf16 [1024*KP] then h bf16 [16384*KP]
    short* Wb = (short*)d_ws;
    short* h  = (short*)((char*)d_ws + (size_t)NOUT * KP * sizeof(short));

    prep   <<<dim3(MROWS + NOUT), dim3(256), 0, stream>>>(x, W, h, Wb);
    gemm_bt<<<dim3(MROWS / 128, NOUT / 128), dim3(256), 0, stream>>>(h, Wb, bias, out);
}